// Round 6
// baseline (219.283 us; speedup 1.0000x reference)
//
#include <hip/hip_runtime.h>
#include <hip/hip_bf16.h>
#include <stdint.h>

typedef unsigned short u16;

#define Bdim 8
#define Ldim 2048
#define Ddim 1024
#define NH 16
#define HD 64
#define MTOK (Bdim*Ldim)   // 16384

typedef __bf16 bf16x8 __attribute__((ext_vector_type(8)));
typedef float  f32x4  __attribute__((ext_vector_type(4)));
typedef float  f32x16 __attribute__((ext_vector_type(16)));

#define AS1 __attribute__((address_space(1)))
#define AS3 __attribute__((address_space(3)))

__device__ __forceinline__ void gload_lds16(const void* g, void* l) {
  __builtin_amdgcn_global_load_lds((const AS1 void*)g, (AS3 void*)l, 16, 0, 0);
}

__device__ __forceinline__ u16 f2bf(float f) {
  uint32_t u = __builtin_bit_cast(uint32_t, f);
  u += 0x7fffu + ((u >> 16) & 1u);   // round-to-nearest-even
  return (u16)(u >> 16);
}
__device__ __forceinline__ uint32_t pkpair(float lo, float hi) {
  return (uint32_t)f2bf(lo) | ((uint32_t)f2bf(hi) << 16);
}

// ---------------- fp32 -> bf16 convert ---------------------------------------
__global__ __launch_bounds__(256) void conv_f32_bf16(const float* __restrict__ in,
                                                     u16* __restrict__ out, int n4) {
  int i = blockIdx.x * 256 + threadIdx.x;
  if (i < n4) {
    float4 v = ((const float4*)in)[i];
    uint32_t w0 = (uint32_t)f2bf(v.x) | ((uint32_t)f2bf(v.y) << 16);
    uint32_t w1 = (uint32_t)f2bf(v.z) | ((uint32_t)f2bf(v.w) << 16);
    ((uint2*)out)[i] = make_uint2(w0, w1);
  }
}

// ---------------- W[K][N] fp32 -> Wt[N][K] bf16 (tiled transpose) ------------
__global__ __launch_bounds__(256) void conv_transpose_w(const float* __restrict__ W,
                                                        u16* __restrict__ Wt) {
  __shared__ float t[32][33];
  int tx = threadIdx.x & 31, ty = threadIdx.x >> 5;
  int k0 = blockIdx.x * 32, n0 = blockIdx.y * 32;
  #pragma unroll
  for (int i = 0; i < 32; i += 8)
    t[ty + i][tx] = W[(size_t)(k0 + ty + i) * Ddim + n0 + tx];
  __syncthreads();
  #pragma unroll
  for (int i = 0; i < 32; i += 8)
    Wt[(size_t)(n0 + ty + i) * Ddim + k0 + tx] = f2bf(t[tx][ty + i]);
}

// ---------------- 128x256 double-buffered GEMM, 2 blocks/CU -------------------
// 512 thr = 8 waves (2Mx4N), per-wave 64x64 (acc[4][4] = 64 VGPR). BK=32,
// LDS 48KB (2 buf x (A 8KB + B 16KB)) -> with <=128 VGPR two blocks co-reside
// per CU; one block's barrier stalls hide under the other's MFMAs.
// Per tile: BAR; STAGE(t+1) (3 gload_lds); vmcnt(3) [counted - tile t staged
// one full tile earlier]; BAR; 8 ds_read_b128 + 16 MFMA (setprio-wrapped).
// Swizzle: 64B rows; phys chunk = logical chunk ^ ((row>>1)&3) applied on the
// GLOBAL source (linear LDS dest) and on the ds_read -> 2-way conflicts (free).
template <int FUSED>
__global__ __launch_bounds__(512, 4) void gemmDP(const u16* __restrict__ A,
                                                 const u16* __restrict__ Bt,
                                                 const float* __restrict__ b0p,
                                                 const float* __restrict__ b1p,
                                                 const float* __restrict__ b2p,
                                                 void* __restrict__ o0,
                                                 void* __restrict__ o1,
                                                 void* __restrict__ o2) {
  __shared__ alignas(16) u16 LP[24576];            // 48 KB
  const int tid = threadIdx.x;
  const int wid = tid >> 6, lane = tid & 63;
  const int wr = wid >> 2, wc = wid & 3;           // 2x4 wave grid
  const int fr = lane & 15, fh = lane >> 4;
  const int key = (fr >> 1) & 3;                   // read-side swizzle key

  // XCD-aware mapping: 16 mt-tiles fast within each XCD, nt slow
  const int bid = blockIdx.x;
  const int xcd = bid & 7, idx = bid >> 3;
  const int mt = xcd * 16 + (idx & 15);
  const int nt = idx >> 4;                          // FUSED: 0..11, else 0..3
  const int m0 = mt * 128, n0g = nt * 256;

  // staging mapping: thread -> (row = tid>>2, chunk = tid&3), source column
  // pre-swizzled so linear LDS + swizzled read match.
  const int sr  = tid >> 2;                         // 0..127
  const int sgc = ((tid & 3) ^ ((tid >> 3) & 3)) * 8;
  const u16* aS  = A  + (size_t)(m0 + sr)        * 1024 + sgc;
  const u16* bS0 = Bt + (size_t)(n0g + sr)       * 1024 + sgc;
  const u16* bS1 = Bt + (size_t)(n0g + 128 + sr) * 1024 + sgc;
  const int ldA = wid * 512;                        // u16 offsets (wave-uniform)

#define STG(T, B_) do {                                                        \
    gload_lds16(aS  + (T) * 32, LP + (B_) * 12288 + ldA);                      \
    gload_lds16(bS0 + (T) * 32, LP + (B_) * 12288 + 4096 + ldA);               \
    gload_lds16(bS1 + (T) * 32, LP + (B_) * 12288 + 8192 + ldA);               \
  } while (0)

#define WAITV(N) asm volatile("s_waitcnt vmcnt(" #N ")" ::: "memory")
#define BAR() __builtin_amdgcn_s_barrier()

  f32x4 acc[4][4] = {};

#define COMPUTE(B_) do {                                                       \
    const u16* la_ = LP + (B_) * 12288;                                        \
    const u16* lb_ = la_ + 4096;                                               \
    const int p_ = (fh ^ key) * 8;                                             \
    bf16x8 bf_[4];                                                             \
    _Pragma("unroll")                                                          \
    for (int n_ = 0; n_ < 4; ++n_)                                             \
      bf_[n_] = *(const bf16x8*)(lb_ + (wc * 64 + n_ * 16 + fr) * 32 + p_);    \
    __builtin_amdgcn_s_setprio(1);                                             \
    _Pragma("unroll")                                                          \
    for (int m_ = 0; m_ < 4; ++m_) {                                           \
      bf16x8 am_ = *(const bf16x8*)(la_ + (wr * 64 + m_ * 16 + fr) * 32 + p_); \
      _Pragma("unroll")                                                        \
      for (int n_ = 0; n_ < 4; ++n_)                                           \
        acc[m_][n_] = __builtin_amdgcn_mfma_f32_16x16x32_bf16(                 \
            am_, bf_[n_], acc[m_][n_], 0, 0, 0);                               \
    }                                                                          \
    __builtin_amdgcn_s_setprio(0);                                             \
  } while (0)

  STG(0, 0);                                        // prologue
  #pragma unroll 1
  for (int t = 0; t < 31; ++t) {
    const int b = t & 1;
    BAR();                       // all waves done reading buf b^1 (tile t-1)
    STG(t + 1, b ^ 1);           // prefetch next tile into the dead buffer
    WAITV(3);                    // retire tile t's loads (issued 1 tile ago)
    BAR();                       // tile t visible to all waves
    COMPUTE(b);
  }
  BAR();
  WAITV(0);                      // tail: tile 31
  BAR();
  COMPUTE(1);
  __syncthreads();               // LDS reuse below

  if (FUSED) {
    const int which = nt >> 2;                      // 0 Q, 1 K, 2 V
    const int n0l = (nt & 3) * 256;
    const float* bias = which == 0 ? b0p : which == 1 ? b1p : b2p;
    u16* Out = (u16*)(which == 0 ? o0 : which == 1 ? o1 : o2);
    u16* Ct = LP;                                   // [128][136] u16 (34.8KB)
    #pragma unroll 1
    for (int h = 0; h < 2; ++h) {                   // col halves of 128
      if (h) __syncthreads();
      if ((wc >> 1) == h) {
        #pragma unroll
        for (int n = 0; n < 4; ++n) {
          float bvv = bias[n0l + h * 128 + (wc & 1) * 64 + n * 16 + fr];
          #pragma unroll
          for (int m = 0; m < 4; ++m)
            #pragma unroll
            for (int r = 0; r < 4; ++r)
              Ct[(wr * 64 + m * 16 + fh * 4 + r) * 136 +
                 (wc & 1) * 64 + n * 16 + fr] = f2bf(acc[m][n][r] + bvv);
        }
      }
      __syncthreads();
      if (which != 2) {
        #pragma unroll
        for (int j = 0; j < 4; ++j) {
          int unit = j * 512 + tid, row = unit >> 4, c8 = unit & 15;
          uint4 v = *(const uint4*)(Ct + row * 136 + c8 * 8);
          *(uint4*)(Out + (size_t)(m0 + row) * Ddim + n0l + h * 128 + c8 * 8) = v;
        }
      } else {
        // V per-token transposed: Vt[i=d&15][k=d>>4]
        #pragma unroll
        for (int j = 0; j < 4; ++j) {
          int unit = j * 512 + tid, row = unit >> 4, i = unit & 15;
          u16 tmp[8];
          #pragma unroll
          for (int jj = 0; jj < 8; ++jj) tmp[jj] = Ct[row * 136 + i + 16 * jj];
          *(uint4*)(Out + (size_t)(m0 + row) * Ddim + i * 64 +
                    (n0l >> 4) + h * 8) = *(uint4*)tmp;
        }
      }
      __syncthreads();
    }
  } else {
    float* Cf = (float*)LP;                         // [128][68] f32 (34.8KB)
    float* Out = (float*)o0;
    #pragma unroll 1
    for (int h = 0; h < 4; ++h) {                   // col quarters of 64
      if (h) __syncthreads();
      if (wc == h) {
        #pragma unroll
        for (int n = 0; n < 4; ++n) {
          float bvv = b0p[n0g + h * 64 + n * 16 + fr];
          #pragma unroll
          for (int m = 0; m < 4; ++m)
            #pragma unroll
            for (int r = 0; r < 4; ++r)
              Cf[(wr * 64 + m * 16 + fh * 4 + r) * 68 + n * 16 + fr] =
                  acc[m][n][r] + bvv;
        }
      }
      __syncthreads();
      #pragma unroll
      for (int j = 0; j < 4; ++j) {
        int unit = j * 512 + tid, row = unit >> 4, c4 = unit & 15;
        float4 v = *(const float4*)(Cf + row * 68 + c4 * 4);
        *(float4*)(Out + (size_t)(m0 + row) * Ddim + n0g + h * 64 + c4 * 4) = v;
      }
      __syncthreads();
    }
  }
#undef STG
#undef WAITV
#undef BAR
#undef COMPUTE
}

// ---------------- per-token attention via MFMA (unchanged, verified) ---------
__global__ __launch_bounds__(256) void attn_mfma(const u16* __restrict__ Q,
                                                 const u16* __restrict__ Kb,
                                                 const u16* __restrict__ Vt,
                                                 u16* __restrict__ Y) {
  const int wid = threadIdx.x >> 6, lane = threadIdx.x & 63;
  const int tok = blockIdx.x * 4 + wid;
  const size_t base = (size_t)tok * Ddim;
  const int hi = lane >> 5, c31 = lane & 31;

  const bf16x8 kf0 = *(const bf16x8*)(Kb + base + (size_t)c31 * NH + hi * 8);
  const bf16x8 kf1 = *(const bf16x8*)(Kb + base + (size_t)(32 + c31) * NH + hi * 8);
  const bf16x8 qf0 = *(const bf16x8*)(Q  + base + (size_t)c31 * NH + hi * 8);
  const bf16x8 qf1 = *(const bf16x8*)(Q  + base + (size_t)(32 + c31) * NH + hi * 8);
  bf16x8 bv[4];
  #pragma unroll
  for (int c = 0; c < 4; ++c)
    bv[c] = *(const bf16x8*)(Vt + base + (size_t)(lane & 15) * HD + c * 16 + hi * 8);

  const f32x16 z = {};
  f32x16 s00 = __builtin_amdgcn_mfma_f32_32x32x16_bf16(kf0, qf0, z, 0, 0, 0);
  f32x16 s01 = __builtin_amdgcn_mfma_f32_32x32x16_bf16(kf0, qf1, z, 0, 0, 0);
  f32x16 s11 = __builtin_amdgcn_mfma_f32_32x32x16_bf16(kf1, qf1, z, 0, 0, 0);

  float a[16], b0[16], b1[16];
  float mA = -3e38f, mB = -3e38f;
  #pragma unroll
  for (int r = 0; r < 16; ++r) {
    const int kl = (r & 3) + 8 * (r >> 2) + 4 * hi;
    const bool keep = kl <= c31;
    float v00 = fmaf(s00[r], 0.25f, 1e-6f);
    float v01 = fmaf(s01[r], 0.25f, 1e-6f);
    float v11 = fmaf(s11[r], 0.25f, 1e-6f);
    a[r]  = keep ? v00 : -3e38f;
    b0[r] = v01;
    b1[r] = keep ? v11 : -3e38f;
    mA = fmaxf(mA, a[r]);
    mB = fmaxf(mB, fmaxf(b0[r], b1[r]));
  }
  mA = fmaxf(mA, __shfl_xor(mA, 32, 64));
  mB = fmaxf(mB, __shfl_xor(mB, 32, 64));
  float sA = 0.f, sB = 0.f;
  #pragma unroll
  for (int r = 0; r < 16; ++r) {
    a[r]  = __expf(a[r]  - mA);  sA += a[r];
    b0[r] = __expf(b0[r] - mB);
    b1[r] = __expf(b1[r] - mB);  sB += b0[r] + b1[r];
  }
  sA += __shfl_xor(sA, 32, 64);
  sB += __shfl_xor(sB, 32, 64);
  const float iA = __builtin_amdgcn_rcpf(sA);
  const float iB = __builtin_amdgcn_rcpf(sB);

  uint32_t pA[4][2], pB0[4][2], pB1[4][2];
  #pragma unroll
  for (int m = 0; m < 4; ++m)
    #pragma unroll
    for (int t = 0; t < 2; ++t) {
      pA [m][t] = pkpair(a [4*m+2*t] * iA, a [4*m+2*t+1] * iA);
      pB0[m][t] = pkpair(b0[4*m+2*t] * iB, b0[4*m+2*t+1] * iB);
      pB1[m][t] = pkpair(b1[4*m+2*t] * iB, b1[4*m+2*t+1] * iB);
    }

#define AFRAG(dst, src, cp) do {                                              \
    uint32_t k0_ = hi ? src[2*(cp)+1][0] : src[2*(cp)][0];                    \
    uint32_t k1_ = hi ? src[2*(cp)+1][1] : src[2*(cp)][1];                    \
    uint32_t s0_ = hi ? src[2*(cp)][0]   : src[2*(cp)+1][0];                  \
    uint32_t s1_ = hi ? src[2*(cp)][1]   : src[2*(cp)+1][1];                  \
    uint32_t r0_ = (uint32_t)__shfl_xor((int)s0_, 32, 64);                    \
    uint32_t r1_ = (uint32_t)__shfl_xor((int)s1_, 32, 64);                    \
    union { uint32_t w[4]; bf16x8 v; } u_;                                    \
    u_.w[0] = hi ? r0_ : k0_;  u_.w[1] = hi ? r1_ : k1_;                      \
    u_.w[2] = hi ? k0_ : r0_;  u_.w[3] = hi ? k1_ : r1_;                      \
    dst = u_.v;                                                               \
  } while (0)

  f32x16 y0 = {}, y1 = {};
  bf16x8 af;
  AFRAG(af, pA, 0);  y0 = __builtin_amdgcn_mfma_f32_32x32x16_bf16(af, bv[0], y0, 0, 0, 0);
  AFRAG(af, pA, 1);  y0 = __builtin_amdgcn_mfma_f32_32x32x16_bf16(af, bv[1], y0, 0, 0, 0);
  AFRAG(af, pB0, 0); y1 = __builtin_amdgcn_mfma_f32_32x32x16_bf16(af, bv[0], y1, 0, 0, 0);
  AFRAG(af, pB0, 1); y1 = __builtin_amdgcn_mfma_f32_32x32x16_bf16(af, bv[1], y1, 0, 0, 0);
  AFRAG(af, pB1, 0); y1 = __builtin_amdgcn_mfma_f32_32x32x16_bf16(af, bv[2], y1, 0, 0, 0);
  AFRAG(af, pB1, 1); y1 = __builtin_amdgcn_mfma_f32_32x32x16_bf16(af, bv[3], y1, 0, 0, 0);
#undef AFRAG

  if (c31 < 16) {
    #pragma unroll
    for (int r = 0; r < 16; ++r) {
      const int row = (r & 3) + 8 * (r >> 2) + 4 * hi;
      Y[base + (size_t)row * NH + c31]        = f2bf(y0[r]);
      Y[base + (size_t)(32 + row) * NH + c31] = f2bf(y1[r]);
    }
  }
}

// ---------------- launch ------------------------------------------------------
extern "C" void kernel_launch(void* const* d_in, const int* in_sizes, int n_in,
                              void* d_out, int out_size, void* d_ws, size_t ws_size,
                              hipStream_t stream) {
  const float* x  = (const float*)d_in[0];
  const float* Wq = (const float*)d_in[1];
  const float* bq = (const float*)d_in[2];
  const float* Wk = (const float*)d_in[3];
  const float* bk = (const float*)d_in[4];
  const float* Wv = (const float*)d_in[5];
  const float* bv = (const float*)d_in[6];
  const float* Wo = (const float*)d_in[7];
  const float* bo = (const float*)d_in[8];
  float* out = (float*)d_out;

  u16* xb = (u16*)d_ws;                          // [16384][1024]
  u16* Wt = xb + (size_t)MTOK * Ddim;            // 4 x [1024][1024] transposed (q,k,v,o)
  u16* Qb = Wt + 4ull * Ddim * Ddim;
  u16* Kb = Qb + (size_t)MTOK * Ddim;
  u16* Vb = Kb + (size_t)MTOK * Ddim;            // Vt (per-token [nh][hd])
  u16* Yb = xb;                                  // reuse xb after attention

  conv_f32_bf16<<<(MTOK * Ddim / 4 + 255) / 256, 256, 0, stream>>>(x, xb, MTOK * Ddim / 4);

  dim3 tg(Ddim / 32, Ddim / 32);
  conv_transpose_w<<<tg, 256, 0, stream>>>(Wq, Wt + 0ull * Ddim * Ddim);
  conv_transpose_w<<<tg, 256, 0, stream>>>(Wk, Wt + 1ull * Ddim * Ddim);
  conv_transpose_w<<<tg, 256, 0, stream>>>(Wv, Wt + 2ull * Ddim * Ddim);
  conv_transpose_w<<<tg, 256, 0, stream>>>(Wo, Wt + 3ull * Ddim * Ddim);

  // fused QKV: Bt = [Wq^T | Wk^T | Wv^T]; grid = 128 mt x 12 nt = 1536 blocks
  gemmDP<1><<<dim3(1536), 512, 0, stream>>>(xb, Wt, bq, bk, bv, Qb, Kb, Vb);

  attn_mfma<<<MTOK / 4, 256, 0, stream>>>(Qb, Kb, Vb, Yb);

  // output projection: 128 mt x 4 nt = 512 blocks
  gemmDP<0><<<dim3(512), 512, 0, stream>>>(Yb, Wt + 3ull * Ddim * Ddim,
                                           bo, bo, bo, out, out, out);
}

// Round 7
// 209.119 us; speedup vs baseline: 1.0486x; 1.0486x over previous
//
#include <hip/hip_runtime.h>
#include <hip/hip_bf16.h>
#include <stdint.h>

typedef unsigned short u16;

#define Bdim 8
#define Ldim 2048
#define Ddim 1024
#define NH 16
#define HD 64
#define MTOK (Bdim*Ldim)   // 16384

typedef __bf16 bf16x8 __attribute__((ext_vector_type(8)));
typedef float  f32x4  __attribute__((ext_vector_type(4)));
typedef float  f32x16 __attribute__((ext_vector_type(16)));

#define AS1 __attribute__((address_space(1)))
#define AS3 __attribute__((address_space(3)))

__device__ __forceinline__ void gload_lds16(const void* g, void* l) {
  __builtin_amdgcn_global_load_lds((const AS1 void*)g, (AS3 void*)l, 16, 0, 0);
}

__device__ __forceinline__ u16 f2bf(float f) {
  uint32_t u = __builtin_bit_cast(uint32_t, f);
  u += 0x7fffu + ((u >> 16) & 1u);   // round-to-nearest-even
  return (u16)(u >> 16);
}
__device__ __forceinline__ uint32_t pkpair(float lo, float hi) {
  return (uint32_t)f2bf(lo) | ((uint32_t)f2bf(hi) << 16);
}

// ---------------- fp32 -> bf16 convert ---------------------------------------
__global__ __launch_bounds__(256) void conv_f32_bf16(const float* __restrict__ in,
                                                     u16* __restrict__ out, int n4) {
  int i = blockIdx.x * 256 + threadIdx.x;
  if (i < n4) {
    float4 v = ((const float4*)in)[i];
    uint32_t w0 = (uint32_t)f2bf(v.x) | ((uint32_t)f2bf(v.y) << 16);
    uint32_t w1 = (uint32_t)f2bf(v.z) | ((uint32_t)f2bf(v.w) << 16);
    ((uint2*)out)[i] = make_uint2(w0, w1);
  }
}

// ---------------- W[K][N] fp32 -> Wt[N][K] bf16 (tiled transpose) ------------
__global__ __launch_bounds__(256) void conv_transpose_w(const float* __restrict__ W,
                                                        u16* __restrict__ Wt) {
  __shared__ float t[32][33];
  int tx = threadIdx.x & 31, ty = threadIdx.x >> 5;
  int k0 = blockIdx.x * 32, n0 = blockIdx.y * 32;
  #pragma unroll
  for (int i = 0; i < 32; i += 8)
    t[ty + i][tx] = W[(size_t)(k0 + ty + i) * Ddim + n0 + tx];
  __syncthreads();
  #pragma unroll
  for (int i = 0; i < 32; i += 8)
    Wt[(size_t)(n0 + ty + i) * Ddim + k0 + tx] = f2bf(t[tx][ty + i]);
}

// ---------------- 256x256 8-phase GEMM (m201-template port) ------------------
// 512 thr = 8 waves (2Mx4N), per-wave 128x64 (acc[8][4]). BK=64; iter = 2
// K-tiles (buf0 even tile, buf1 odd), 8 phases/iter. Phase: {ds_read next
// phase's frags; stage 1 half-tile (2 gload_lds); barrier; setprio+16 MFMA;
// [vmcnt(2) @ p2,p6]; barrier}. Frag regs double-buffered. LDS swizzle:
// 16B-block XOR (row&7), pre-swizzled global src + XOR'd ds_read.
// Hazard audit (per-region): stage@p >= last-read@p-1 + bar2; read gated by
// vmcnt(2)+bar covering all its staging loads.
template <int FUSED>
__global__ __launch_bounds__(512, 2) void gemm8p(const u16* __restrict__ A,
                                                 const u16* __restrict__ Bt,
                                                 const float* __restrict__ b0p,
                                                 const float* __restrict__ b1p,
                                                 const float* __restrict__ b2p,
                                                 void* __restrict__ o0,
                                                 void* __restrict__ o1,
                                                 void* __restrict__ o2) {
  __shared__ alignas(16) u16 LP[65536];            // 128 KB: A[2][256][64] | B[2][256][64]
  const int tid = threadIdx.x;
  const int wid = tid >> 6, lane = tid & 63;
  const int wr = wid >> 2, wc = wid & 3;           // 2x4 wave grid
  const int fr = lane & 15, fh = lane >> 4;

  const int bid = blockIdx.x;
  const int xcd = bid & 7, idx = bid >> 3;
  const int mt = xcd * 8 + (idx & 7);
  const int nt = idx >> 3;                          // FUSED: 0..11, else 0..3
  const int m0 = mt * 256, n0g = nt * 256;

  // ds_read addressing (u16 units); logical 16B-block b read at phys b^(row&7)
  const int x7 = fr & 7;
  const int cks0 = (fh ^ x7) * 8;
  const int cks1 = ((4 + fh) ^ x7) * 8;
  const int rA = (wr * 128 + fr) * 64;
  const int rB = (wc * 64 + fr) * 64;

  // staging source (pre-swizzled global col so linear LDS dest = swizzled layout)
  const int srt = tid >> 3;                         // 0..63
  const int sgc = ((tid & 7) ^ (srt & 7)) * 8;
  const u16* aSt = A  + (size_t)(m0  + srt) * 1024 + sgc;
  const u16* bSt = Bt + (size_t)(n0g + srt) * 1024 + sgc;

#define RDA4(DST, B_, KS_, MH_) do {                                           \
    const u16* p_ = LP + (B_) * 16384 + rA + (MH_) * 4096 + ((KS_) ? cks1 : cks0); \
    DST[0] = *(const bf16x8*)(p_);                                             \
    DST[1] = *(const bf16x8*)(p_ + 1024);                                      \
    DST[2] = *(const bf16x8*)(p_ + 2048);                                      \
    DST[3] = *(const bf16x8*)(p_ + 3072);                                      \
  } while (0)
#define RDB4(DST, B_, KS_) do {                                                \
    const u16* p_ = LP + 32768 + (B_) * 16384 + rB + ((KS_) ? cks1 : cks0);    \
    DST[0] = *(const bf16x8*)(p_);                                             \
    DST[1] = *(const bf16x8*)(p_ + 1024);                                      \
    DST[2] = *(const bf16x8*)(p_ + 2048);                                      \
    DST[3] = *(const bf16x8*)(p_ + 3072);                                      \
  } while (0)
  // stage half H_ (128 rows) of K-tile T_ into buffer B_ (2 x gload_lds/thread)
#define STGH(ISB_, T_, H_, B_) do {                                            \
    const u16* s_ = ((ISB_) ? bSt : aSt) + (size_t)(H_) * 131072 + (size_t)(T_) * 64; \
    u16* d_ = (u16*)LP + ((ISB_) ? 32768 : 0) + (B_) * 16384 + (H_) * 8192 + (wid << 9); \
    gload_lds16(s_, d_);                                                       \
    gload_lds16(s_ + 65536, d_ + 4096);                                        \
  } while (0)
#define MFMA16(AF, BF, MH) do {                                                \
    __builtin_amdgcn_s_setprio(1);                                             \
    _Pragma("unroll")                                                          \
    for (int mm_ = 0; mm_ < 4; ++mm_)                                          \
      _Pragma("unroll")                                                        \
      for (int n_ = 0; n_ < 4; ++n_)                                           \
        acc[(MH) * 4 + mm_][n_] = __builtin_amdgcn_mfma_f32_16x16x32_bf16(     \
            AF[mm_], BF[n_], acc[(MH) * 4 + mm_][n_], 0, 0, 0);                \
    __builtin_amdgcn_s_setprio(0);                                             \
  } while (0)
#define WAITV(N) asm volatile("s_waitcnt vmcnt(" #N ")" ::: "memory")
#define BAR() do { asm volatile("" ::: "memory");                              \
                   __builtin_amdgcn_s_barrier();                               \
                   asm volatile("" ::: "memory"); } while (0)

  f32x4 acc[8][4] = {};
  bf16x8 aA[4], aB[4], bA[4], bB[4];

  // prologue: T0 all 4 halves -> buf0; T1 halves Bh0,Ah0 -> buf1 (12 loads)
  STGH(1, 0, 0, 0); STGH(0, 0, 0, 0); STGH(1, 0, 1, 0); STGH(0, 0, 1, 0);
  STGH(1, 1, 0, 1); STGH(0, 1, 0, 1);
  WAITV(4);                       // T0's 8 loads landed (T1's 4 in flight)
  BAR();
  RDA4(aA, 0, 0, 0); RDB4(bA, 0, 0);   // frags for p0

  #pragma unroll 1
  for (int i = 0; i < 8; ++i) {
    const int u1 = 2 * i + 1;                  // odd tile of this iter
    const int s2 = (i < 7) ? 2 * i + 2 : 14;   // next even tile (clamped)
    const int s3 = (i < 7) ? 2 * i + 3 : 15;   // next odd tile (clamped)
    // p0: MFMA(T,ks0,mA); read A(T,ks0,mB); stage u1.Bh1->buf1
    RDA4(aB, 0, 0, 1);                 STGH(1, u1, 1, 1);
    BAR(); MFMA16(aA, bA, 0); BAR();
    // p1: MFMA(T,ks0,mB); read A(T,ks1,mA)+B(T,ks1); stage u1.Ah1->buf1
    RDA4(aA, 0, 1, 0); RDB4(bB, 0, 1); STGH(0, u1, 1, 1);
    BAR(); MFMA16(aB, bA, 1); BAR();
    // p2: MFMA(T,ks1,mA); read A(T,ks1,mB); stage s2.Bh0->buf0; gate T1
    RDA4(aB, 0, 1, 1);                 STGH(1, s2, 0, 0);
    BAR(); MFMA16(aA, bB, 0); WAITV(2); BAR();
    // p3: MFMA(T,ks1,mB); read A(T1,ks0,mA)+B(T1,ks0); stage s2.Ah0->buf0
    RDA4(aA, 1, 0, 0); RDB4(bA, 1, 0); STGH(0, s2, 0, 0);
    BAR(); MFMA16(aB, bB, 1); BAR();
    // p4: MFMA(T1,ks0,mA); read A(T1,ks0,mB); stage s2.Bh1->buf0
    RDA4(aB, 1, 0, 1);                 STGH(1, s2, 1, 0);
    BAR(); MFMA16(aA, bA, 0); BAR();
    // p5: MFMA(T1,ks0,mB); read A(T1,ks1,mA)+B(T1,ks1); stage s2.Ah1->buf0
    RDA4(aA, 1, 1, 0); RDB4(bB, 1, 1); STGH(0, s2, 1, 0);
    BAR(); MFMA16(aB, bA, 1); BAR();
    // p6: MFMA(T1,ks1,mA); read A(T1,ks1,mB); stage s3.Bh0->buf1; gate T2
    RDA4(aB, 1, 1, 1);                 STGH(1, s3, 0, 1);
    BAR(); MFMA16(aA, bB, 0); WAITV(2); BAR();
    // p7: MFMA(T1,ks1,mB); read A(T2,ks0,mA)+B(T2,ks0); stage s3.Ah0->buf1
    RDA4(aA, 0, 0, 0); RDB4(bA, 0, 0); STGH(0, s3, 0, 1);
    BAR(); MFMA16(aB, bB, 1); BAR();
  }
  __syncthreads();                      // LDS reuse below

  if (FUSED) {
    const int which = nt >> 2;                    // 0 Q, 1 K, 2 V
    const int n0l = (nt & 3) * 256;
    const float* bias = which == 0 ? b0p : which == 1 ? b1p : b2p;
    u16* Out = (u16*)(which == 0 ? o0 : which == 1 ? o1 : o2);
    u16* Ct = LP;                                 // [4 regions][128][72] u16
    #pragma unroll 1
    for (int h = 0; h < 2; ++h) {
      if (h) __syncthreads();
      if (wr == h) {
        #pragma unroll
        for (int n = 0; n < 4; ++n) {
          float bvv = bias[n0l + wc * 64 + n * 16 + fr];
          #pragma unroll
          for (int m = 0; m < 8; ++m)
            #pragma unroll
            for (int r = 0; r < 4; ++r)
              Ct[wc * 9216 + (m * 16 + fh * 4 + r) * 72 + n * 16 + fr] =
                  f2bf(acc[m][n][r] + bvv);
        }
      }
      __syncthreads();
      if (which != 2) {
        #pragma unroll
        for (int j = 0; j < 8; ++j) {
          int r = j * 16 + (tid >> 5), c8 = tid & 31;
          uint4 v = *(const uint4*)(Ct + (c8 >> 3) * 9216 + r * 72 + (c8 & 7) * 8);
          *(uint4*)(Out + (size_t)(m0 + h * 128 + r) * Ddim + n0l + c8 * 8) = v;
        }
      } else {
        // V per-token transposed: Vt[i=d&15][k=d>>4]
        #pragma unroll
        for (int j = 0; j < 4; ++j) {
          int q = j * 512 + tid, r = q >> 4, ii = q & 15;
          u16 tmp[16];
          #pragma unroll
          for (int jj = 0; jj < 16; ++jj) {
            int c = ii + 16 * jj;
            tmp[jj] = Ct[(c >> 6) * 9216 + r * 72 + (c & 63)];
          }
          u16* dst = Out + (size_t)(m0 + h * 128 + r) * Ddim + ii * 64 + (n0l >> 4);
          *(uint4*)dst = *(uint4*)tmp;
          *(uint4*)(dst + 8) = *(uint4*)(tmp + 8);
        }
      }
      __syncthreads();
    }
  } else {
    float* Cf = (float*)LP;                       // [2 regions][128][68] f32
    float* Out = (float*)o0;
    #pragma unroll 1
    for (int h = 0; h < 4; ++h) {                 // (mh = h>>1, nh = h&1)
      if (h) __syncthreads();
      if (wr == (h >> 1) && (wc >> 1) == (h & 1)) {
        #pragma unroll
        for (int n = 0; n < 4; ++n) {
          float bvv = b0p[n0g + (h & 1) * 128 + (wc & 1) * 64 + n * 16 + fr];
          #pragma unroll
          for (int m = 0; m < 8; ++m)
            #pragma unroll
            for (int r = 0; r < 4; ++r)
              Cf[(wc & 1) * 8704 + (m * 16 + fh * 4 + r) * 68 + n * 16 + fr] =
                  acc[m][n][r] + bvv;
        }
      }
      __syncthreads();
      #pragma unroll
      for (int j = 0; j < 8; ++j) {
        int r = j * 16 + (tid >> 5), c4 = tid & 31;
        float4 v = *(const float4*)(Cf + (c4 >> 4) * 8704 + r * 68 + (c4 & 15) * 4);
        *(float4*)(Out + (size_t)(m0 + (h >> 1) * 128 + r) * Ddim +
                   n0g + (h & 1) * 128 + c4 * 4) = v;
      }
      __syncthreads();
    }
  }
#undef RDA4
#undef RDB4
#undef STGH
#undef MFMA16
#undef WAITV
#undef BAR
}

// ---------------- per-token attention via MFMA (unchanged, verified) ---------
__global__ __launch_bounds__(256) void attn_mfma(const u16* __restrict__ Q,
                                                 const u16* __restrict__ Kb,
                                                 const u16* __restrict__ Vt,
                                                 u16* __restrict__ Y) {
  const int wid = threadIdx.x >> 6, lane = threadIdx.x & 63;
  const int tok = blockIdx.x * 4 + wid;
  const size_t base = (size_t)tok * Ddim;
  const int hi = lane >> 5, c31 = lane & 31;

  const bf16x8 kf0 = *(const bf16x8*)(Kb + base + (size_t)c31 * NH + hi * 8);
  const bf16x8 kf1 = *(const bf16x8*)(Kb + base + (size_t)(32 + c31) * NH + hi * 8);
  const bf16x8 qf0 = *(const bf16x8*)(Q  + base + (size_t)c31 * NH + hi * 8);
  const bf16x8 qf1 = *(const bf16x8*)(Q  + base + (size_t)(32 + c31) * NH + hi * 8);
  bf16x8 bv[4];
  #pragma unroll
  for (int c = 0; c < 4; ++c)
    bv[c] = *(const bf16x8*)(Vt + base + (size_t)(lane & 15) * HD + c * 16 + hi * 8);

  const f32x16 z = {};
  f32x16 s00 = __builtin_amdgcn_mfma_f32_32x32x16_bf16(kf0, qf0, z, 0, 0, 0);
  f32x16 s01 = __builtin_amdgcn_mfma_f32_32x32x16_bf16(kf0, qf1, z, 0, 0, 0);
  f32x16 s11 = __builtin_amdgcn_mfma_f32_32x32x16_bf16(kf1, qf1, z, 0, 0, 0);

  float a[16], b0[16], b1[16];
  float mA = -3e38f, mB = -3e38f;
  #pragma unroll
  for (int r = 0; r < 16; ++r) {
    const int kl = (r & 3) + 8 * (r >> 2) + 4 * hi;
    const bool keep = kl <= c31;
    float v00 = fmaf(s00[r], 0.25f, 1e-6f);
    float v01 = fmaf(s01[r], 0.25f, 1e-6f);
    float v11 = fmaf(s11[r], 0.25f, 1e-6f);
    a[r]  = keep ? v00 : -3e38f;
    b0[r] = v01;
    b1[r] = keep ? v11 : -3e38f;
    mA = fmaxf(mA, a[r]);
    mB = fmaxf(mB, fmaxf(b0[r], b1[r]));
  }
  mA = fmaxf(mA, __shfl_xor(mA, 32, 64));
  mB = fmaxf(mB, __shfl_xor(mB, 32, 64));
  float sA = 0.f, sB = 0.f;
  #pragma unroll
  for (int r = 0; r < 16; ++r) {
    a[r]  = __expf(a[r]  - mA);  sA += a[r];
    b0[r] = __expf(b0[r] - mB);
    b1[r] = __expf(b1[r] - mB);  sB += b0[r] + b1[r];
  }
  sA += __shfl_xor(sA, 32, 64);
  sB += __shfl_xor(sB, 32, 64);
  const float iA = __builtin_amdgcn_rcpf(sA);
  const float iB = __builtin_amdgcn_rcpf(sB);

  uint32_t pA[4][2], pB0[4][2], pB1[4][2];
  #pragma unroll
  for (int m = 0; m < 4; ++m)
    #pragma unroll
    for (int t = 0; t < 2; ++t) {
      pA [m][t] = pkpair(a [4*m+2*t] * iA, a [4*m+2*t+1] * iA);
      pB0[m][t] = pkpair(b0[4*m+2*t] * iB, b0[4*m+2*t+1] * iB);
      pB1[m][t] = pkpair(b1[4*m+2*t] * iB, b1[4*m+2*t+1] * iB);
    }

#define AFRAG(dst, src, cp) do {                                              \
    uint32_t k0_ = hi ? src[2*(cp)+1][0] : src[2*(cp)][0];                    \
    uint32_t k1_ = hi ? src[2*(cp)+1][1] : src[2*(cp)][1];                    \
    uint32_t s0_ = hi ? src[2*(cp)][0]   : src[2*(cp)+1][0];                  \
    uint32_t s1_ = hi ? src[2*(cp)][1]   : src[2*(cp)+1][1];                  \
    uint32_t r0_ = (uint32_t)__shfl_xor((int)s0_, 32, 64);                    \
    uint32_t r1_ = (uint32_t)__shfl_xor((int)s1_, 32, 64);                    \
    union { uint32_t w[4]; bf16x8 v; } u_;                                    \
    u_.w[0] = hi ? r0_ : k0_;  u_.w[1] = hi ? r1_ : k1_;                      \
    u_.w[2] = hi ? k0_ : r0_;  u_.w[3] = hi ? k1_ : r1_;                      \
    dst = u_.v;                                                               \
  } while (0)

  f32x16 y0 = {}, y1 = {};
  bf16x8 af;
  AFRAG(af, pA, 0);  y0 = __builtin_amdgcn_mfma_f32_32x32x16_bf16(af, bv[0], y0, 0, 0, 0);
  AFRAG(af, pA, 1);  y0 = __builtin_amdgcn_mfma_f32_32x32x16_bf16(af, bv[1], y0, 0, 0, 0);
  AFRAG(af, pB0, 0); y1 = __builtin_amdgcn_mfma_f32_32x32x16_bf16(af, bv[0], y1, 0, 0, 0);
  AFRAG(af, pB0, 1); y1 = __builtin_amdgcn_mfma_f32_32x32x16_bf16(af, bv[1], y1, 0, 0, 0);
  AFRAG(af, pB1, 0); y1 = __builtin_amdgcn_mfma_f32_32x32x16_bf16(af, bv[2], y1, 0, 0, 0);
  AFRAG(af, pB1, 1); y1 = __builtin_amdgcn_mfma_f32_32x32x16_bf16(af, bv[3], y1, 0, 0, 0);
#undef AFRAG

  if (c31 < 16) {
    #pragma unroll
    for (int r = 0; r < 16; ++r) {
      const int row = (r & 3) + 8 * (r >> 2) + 4 * hi;
      Y[base + (size_t)row * NH + c31]        = f2bf(y0[r]);
      Y[base + (size_t)(32 + row) * NH + c31] = f2bf(y1[r]);
    }
  }
}

// ---------------- launch ------------------------------------------------------
extern "C" void kernel_launch(void* const* d_in, const int* in_sizes, int n_in,
                              void* d_out, int out_size, void* d_ws, size_t ws_size,
                              hipStream_t stream) {
  const float* x  = (const float*)d_in[0];
  const float* Wq = (const float*)d_in[1];
  const float* bq = (const float*)d_in[2];
  const float* Wk = (const float*)d_in[3];
  const float* bk = (const float*)d_in[4];
  const float* Wv = (const float*)d_in[5];
  const float* bv = (const float*)d_in[6];
  const float* Wo = (const float*)d_in[7];
  const float* bo = (const float*)d_in[8];
  float* out = (float*)d_out;

  u16* xb = (u16*)d_ws;                          // [16384][1024]
  u16* Wt = xb + (size_t)MTOK * Ddim;            // 4 x [1024][1024] transposed (q,k,v,o)
  u16* Qb = Wt + 4ull * Ddim * Ddim;
  u16* Kb = Qb + (size_t)MTOK * Ddim;
  u16* Vb = Kb + (size_t)MTOK * Ddim;            // Vt (per-token [nh][hd])
  u16* Yb = xb;                                  // reuse xb after attention

  conv_f32_bf16<<<(MTOK * Ddim / 4 + 255) / 256, 256, 0, stream>>>(x, xb, MTOK * Ddim / 4);

  dim3 tg(Ddim / 32, Ddim / 32);
  conv_transpose_w<<<tg, 256, 0, stream>>>(Wq, Wt + 0ull * Ddim * Ddim);
  conv_transpose_w<<<tg, 256, 0, stream>>>(Wk, Wt + 1ull * Ddim * Ddim);
  conv_transpose_w<<<tg, 256, 0, stream>>>(Wv, Wt + 2ull * Ddim * Ddim);
  conv_transpose_w<<<tg, 256, 0, stream>>>(Wo, Wt + 3ull * Ddim * Ddim);

  // fused QKV: Bt = [Wq^T | Wk^T | Wv^T] (3072 rows); 64 mt x 12 nt = 768 blocks
  gemm8p<1><<<dim3(768), 512, 0, stream>>>(xb, Wt, bq, bk, bv, Qb, Kb, Vb);

  attn_mfma<<<MTOK / 4, 256, 0, stream>>>(Qb, Kb, Vb, Yb);

  // output projection: 64 mt x 4 nt = 256 blocks
  gemm8p<0><<<dim3(256), 512, 0, stream>>>(Yb, Wt + 3ull * Ddim * Ddim,
                                           bo, bo, bo, out, out, out);
}